// Round 4
// baseline (227.648 us; speedup 1.0000x reference)
//
#include <hip/hip_runtime.h>

#define LOG2E 1.4426950408889634f

constexpr int Bsz = 4096, Ssz = 128, Isz = 64, MOTOR = 32;
constexpr int BT = 8, R = 4, NT = 512, NQ = 4;   // 512 thr = 128 s x 4 j-quarters; 2 chunks of 4 rows

// ---- prep: fold constants + repack SoA by j-quad ----
// A4[j4*128+s] = (-sigma*log2e) ; B4 = sigma*mu*log2e ; W4 = w*mask*erev
__global__ void ltc_prep(const float* __restrict__ w, const float* __restrict__ sigma,
                         const float* __restrict__ mu, const float* __restrict__ erev,
                         const float* __restrict__ smask,
                         const float* __restrict__ sw, const float* __restrict__ ssig,
                         const float* __restrict__ smu, const float* __restrict__ serev,
                         const float* __restrict__ ssmask,
                         float4* __restrict__ A4, float4* __restrict__ B4, float4* __restrict__ W4,
                         float4* __restrict__ A4s, float4* __restrict__ B4s, float4* __restrict__ W4s)
{
  int idx = blockIdx.x * blockDim.x + threadIdx.x;
  if (idx < (Ssz / 4) * Ssz) {                    // main: 32 j-quads x 128 s
    int j4 = idx >> 7, s = idx & 127;
    float4 a, b, wv;
    #pragma unroll
    for (int jj = 0; jj < 4; ++jj) {
      int e = (j4 * 4 + jj) * Ssz + s;
      float sg = sigma[e];
      (&a.x)[jj] = -sg * LOG2E;
      (&b.x)[jj] = sg * mu[e] * LOG2E;
      (&wv.x)[jj] = w[e] * smask[e] * erev[e];
    }
    A4[idx] = a; B4[idx] = b; W4[idx] = wv;
  } else if (idx < (Ssz / 4) * Ssz + (Isz / 4) * Ssz) {   // sensory: 16 i-quads x 128 s
    int k = idx - (Ssz / 4) * Ssz;
    int i4 = k >> 7, s = k & 127;
    float4 a, b, wv;
    #pragma unroll
    for (int jj = 0; jj < 4; ++jj) {
      int e = (i4 * 4 + jj) * Ssz + s;
      float sg = ssig[e];
      (&a.x)[jj] = -sg * LOG2E;
      (&b.x)[jj] = sg * smu[e] * LOG2E;
      (&wv.x)[jj] = sw[e] * ssmask[e] * serev[e];
    }
    A4s[k] = a; B4s[k] = b; W4s[k] = wv;
  }
}

__launch_bounds__(NT, 4)
__global__ void ltc_main(const float* __restrict__ inputs, const float* __restrict__ states,
                         const float* __restrict__ gleak, const float* __restrict__ vleak,
                         const float* __restrict__ cmv,
                         const float* __restrict__ iw, const float* __restrict__ ib,
                         const float* __restrict__ ow, const float* __restrict__ ob,
                         const float4* __restrict__ A4, const float4* __restrict__ B4,
                         const float4* __restrict__ W4,
                         const float4* __restrict__ A4s, const float4* __restrict__ B4s,
                         const float4* __restrict__ W4s,
                         float* __restrict__ out)
{
  __shared__ float vsh[BT][Ssz];
  __shared__ float xsh[BT][Isz];
  __shared__ float redn[NQ][R][Ssz];   // [writer-quarter][row-in-chunk][s]
  __shared__ float redd[NQ][R][Ssz];

  const int t = threadIdx.x;
  const int s = t & 127;
  const int qt = t >> 7;               // j-quarter 0..3; also row-in-chunk this thread finalizes
  const int b0 = blockIdx.x * BT;

  // stage x = inputs*iw + ib and v = states into LDS
  for (int k = t; k < BT * Isz; k += NT) {
    int r = k >> 6, i = k & 63;
    xsh[r][i] = inputs[(b0 + r) * Isz + i] * iw[i] + ib[i];
  }
  for (int k = t; k < BT * Ssz; k += NT) {
    int r = k >> 7, ss = k & 127;
    vsh[r][ss] = states[(b0 + r) * Ssz + ss];
  }
  const float cmt = cmv[s] * 6.0f;     // cm / (1.0/6)
  const float gl = gleak[s];
  const float gv = gl * vleak[s];
  const float dbase = cmt + gl + 1e-8f;

  // ---- register-resident main tables: this quarter's 8 j-quads ----
  float4 ta[8], tb[8], tw[8];
  {
    const float4* Ab = A4 + (qt * 8) * Ssz + s;
    const float4* Bb = B4 + (qt * 8) * Ssz + s;
    const float4* Wb = W4 + (qt * 8) * Ssz + s;
    #pragma unroll
    for (int q = 0; q < 8; ++q) {
      ta[q] = Ab[q * Ssz];
      tb[q] = Bb[q * Ssz];
      tw[q] = Wb[q * Ssz];
    }
  }
  __syncthreads();

  #pragma unroll 1
  for (int cb = 0; cb < BT; cb += R) {
    // ---- sensory partials over this quarter's i-range (4 quads) ----
    float sn[R] = {0.f, 0.f, 0.f, 0.f}, sd[R] = {0.f, 0.f, 0.f, 0.f};
    #pragma unroll
    for (int q = 0; q < 4; ++q) {
      int iq = qt * 4 + q;
      float4 a4 = A4s[iq * Ssz + s];
      float4 b4 = B4s[iq * Ssz + s];
      float4 w4 = W4s[iq * Ssz + s];
      float4 xq[R];
      #pragma unroll
      for (int r = 0; r < R; ++r) xq[r] = *(const float4*)&xsh[cb + r][iq * 4];
      #pragma unroll
      for (int jj = 0; jj < 4; ++jj) {
        float av = (&a4.x)[jj], bv = (&b4.x)[jj], wv = (&w4.x)[jj];
        #pragma unroll
        for (int r = 0; r < R; ++r) {
          float arg = fmaf(av, (&xq[r].x)[jj], bv);
          float u = __builtin_amdgcn_exp2f(arg);
          float sig = __builtin_amdgcn_rcpf(1.0f + u);
          sn[r] = fmaf(wv, sig, sn[r]);
          sd[r] = fmaf(fabsf(wv), sig, sd[r]);
        }
      }
    }

    // ---- 6 ODE unfolds over this chunk's R rows ----
    #pragma unroll 1
    for (int it = 0; it < 6; ++it) {
      float num[R], den[R];
      #pragma unroll
      for (int r = 0; r < R; ++r) { num[r] = sn[r]; den[r] = sd[r]; }

      #pragma unroll
      for (int q8 = 0; q8 < 8; ++q8) {
        float4 vc[R];
        #pragma unroll
        for (int r = 0; r < R; ++r) vc[r] = *(const float4*)&vsh[cb + r][qt * 32 + q8 * 4];
        #pragma unroll
        for (int jj = 0; jj < 4; ++jj) {
          float av = (&ta[q8].x)[jj], bv = (&tb[q8].x)[jj], wv = (&tw[q8].x)[jj];
          #pragma unroll
          for (int r = 0; r < R; ++r) {
            float arg = fmaf(av, (&vc[r].x)[jj], bv);
            float u = __builtin_amdgcn_exp2f(arg);
            float sig = __builtin_amdgcn_rcpf(1.0f + u);
            num[r] = fmaf(wv, sig, num[r]);
            den[r] = fmaf(fabsf(wv), sig, den[r]);
          }
        }
      }

      #pragma unroll
      for (int r = 0; r < R; ++r) { redn[qt][r][s] = num[r]; redd[qt][r][s] = den[r]; }
      __syncthreads();                 // B1: redn visible; all vsh reads done
      // quarter qt finalizes row cb+qt (only this thread touches vsh[cb+qt][s])
      float fn = redn[0][qt][s] + redn[1][qt][s] + redn[2][qt][s] + redn[3][qt][s];
      float fd = redd[0][qt][s] + redd[1][qt][s] + redd[2][qt][s] + redd[3][qt][s];
      float vo = vsh[cb + qt][s];
      float nn = fmaf(cmt, vo, gv) + fn;
      float dd = dbase + fd;
      vsh[cb + qt][s] = nn * __builtin_amdgcn_rcpf(dd);
      __syncthreads();                 // B2: vsh writes visible; redn free for next unfold
    }
  }

  // ---- outputs: [B*32] motor affine, then [B*128] v_pre ----
  for (int k = t; k < BT * Ssz; k += NT) {
    int r = k >> 7, ss = k & 127;
    out[Bsz * MOTOR + (b0 + r) * Ssz + ss] = vsh[r][ss];
  }
  for (int k = t; k < BT * MOTOR; k += NT) {
    int r = k >> 5, m = k & 31;
    out[(b0 + r) * MOTOR + m] = fmaf(vsh[r][m], ow[m], ob[m]);
  }
}

extern "C" void kernel_launch(void* const* d_in, const int* in_sizes, int n_in,
                              void* d_out, int out_size, void* d_ws, size_t ws_size,
                              hipStream_t stream) {
  const float* inputs = (const float*)d_in[0];
  const float* states = (const float*)d_in[1];
  const float* gleak  = (const float*)d_in[2];
  const float* vleak  = (const float*)d_in[3];
  const float* cmv    = (const float*)d_in[4];
  const float* w      = (const float*)d_in[5];
  const float* sigma  = (const float*)d_in[6];
  const float* mu     = (const float*)d_in[7];
  const float* erev   = (const float*)d_in[8];
  const float* sw     = (const float*)d_in[9];
  const float* ssig   = (const float*)d_in[10];
  const float* smu    = (const float*)d_in[11];
  const float* serev  = (const float*)d_in[12];
  const float* smask  = (const float*)d_in[13];
  const float* ssmask = (const float*)d_in[14];
  const float* iw     = (const float*)d_in[15];
  const float* ib     = (const float*)d_in[16];
  const float* ow     = (const float*)d_in[17];
  const float* ob     = (const float*)d_in[18];

  char* ws = (char*)d_ws;
  float4* A4  = (float4*)(ws);                   // 32*128*16 = 65536
  float4* B4  = (float4*)(ws + 65536);           // 65536
  float4* W4  = (float4*)(ws + 131072);          // 65536
  float4* A4s = (float4*)(ws + 196608);          // 16*128*16 = 32768
  float4* B4s = (float4*)(ws + 229376);          // 32768
  float4* W4s = (float4*)(ws + 262144);          // 32768  (total 294912 B)
  float* out = (float*)d_out;

  constexpr int prep_items = (Ssz / 4) * Ssz + (Isz / 4) * Ssz;   // 6144
  ltc_prep<<<(prep_items + 255) / 256, 256, 0, stream>>>(
      w, sigma, mu, erev, smask, sw, ssig, smu, serev, ssmask, A4, B4, W4, A4s, B4s, W4s);
  ltc_main<<<Bsz / BT, NT, 0, stream>>>(
      inputs, states, gleak, vleak, cmv, iw, ib, ow, ob, A4, B4, W4, A4s, B4s, W4s, out);
}

// Round 5
// 116.270 us; speedup vs baseline: 1.9579x; 1.9579x over previous
//
#include <hip/hip_runtime.h>

#define LOG2E 1.4426950408889634f

constexpr int Bsz = 4096, Ssz = 128, Isz = 64, MOTOR = 32;
constexpr int BT = 8, R = 4, NT = 512, NQ = 4;   // 512 thr = 128 s x 4 j-quarters; 2 chunks of 4 rows

// ---- prep: fold constants + repack SoA by j-quad ----
// A4[j4*128+s] = (-sigma*log2e) ; B4 = sigma*mu*log2e ; W4 = w*mask*erev
__global__ void ltc_prep(const float* __restrict__ w, const float* __restrict__ sigma,
                         const float* __restrict__ mu, const float* __restrict__ erev,
                         const float* __restrict__ smask,
                         const float* __restrict__ sw, const float* __restrict__ ssig,
                         const float* __restrict__ smu, const float* __restrict__ serev,
                         const float* __restrict__ ssmask,
                         float4* __restrict__ A4, float4* __restrict__ B4, float4* __restrict__ W4,
                         float4* __restrict__ A4s, float4* __restrict__ B4s, float4* __restrict__ W4s)
{
  int idx = blockIdx.x * blockDim.x + threadIdx.x;
  if (idx < (Ssz / 4) * Ssz) {                    // main: 32 j-quads x 128 s
    int j4 = idx >> 7, s = idx & 127;
    float4 a, b, wv;
    #pragma unroll
    for (int jj = 0; jj < 4; ++jj) {
      int e = (j4 * 4 + jj) * Ssz + s;
      float sg = sigma[e];
      (&a.x)[jj] = -sg * LOG2E;
      (&b.x)[jj] = sg * mu[e] * LOG2E;
      (&wv.x)[jj] = w[e] * smask[e] * erev[e];
    }
    A4[idx] = a; B4[idx] = b; W4[idx] = wv;
  } else if (idx < (Ssz / 4) * Ssz + (Isz / 4) * Ssz) {   // sensory: 16 i-quads x 128 s
    int k = idx - (Ssz / 4) * Ssz;
    int i4 = k >> 7, s = k & 127;
    float4 a, b, wv;
    #pragma unroll
    for (int jj = 0; jj < 4; ++jj) {
      int e = (i4 * 4 + jj) * Ssz + s;
      float sg = ssig[e];
      (&a.x)[jj] = -sg * LOG2E;
      (&b.x)[jj] = sg * smu[e] * LOG2E;
      (&wv.x)[jj] = sw[e] * ssmask[e] * serev[e];
    }
    A4s[k] = a; B4s[k] = b; W4s[k] = wv;
  }
}

__launch_bounds__(NT, 2)   // cap 256 VGPR; actual ~108 -> 4 waves/SIMD at runtime
__global__ void ltc_main(const float* __restrict__ inputs, const float* __restrict__ states,
                         const float* __restrict__ gleak, const float* __restrict__ vleak,
                         const float* __restrict__ cmv,
                         const float* __restrict__ iw, const float* __restrict__ ib,
                         const float* __restrict__ ow, const float* __restrict__ ob,
                         const float4* __restrict__ A4, const float4* __restrict__ B4,
                         const float4* __restrict__ W4,
                         const float4* __restrict__ A4s, const float4* __restrict__ B4s,
                         const float4* __restrict__ W4s,
                         float* __restrict__ out)
{
  __shared__ float vsh[BT][Ssz];
  __shared__ float xsh[BT][Isz];
  __shared__ float redn[NQ][R][Ssz];   // [writer-quarter][row-in-chunk][s]
  __shared__ float redd[NQ][R][Ssz];

  const int t = threadIdx.x;
  const int s = t & 127;
  const int qt = t >> 7;               // j-quarter 0..3; also row-in-chunk this thread finalizes
  const int b0 = blockIdx.x * BT;

  // stage x = inputs*iw + ib and v = states into LDS
  for (int k = t; k < BT * Isz; k += NT) {
    int r = k >> 6, i = k & 63;
    xsh[r][i] = inputs[(b0 + r) * Isz + i] * iw[i] + ib[i];
  }
  for (int k = t; k < BT * Ssz; k += NT) {
    int r = k >> 7, ss = k & 127;
    vsh[r][ss] = states[(b0 + r) * Ssz + ss];
  }
  const float cmt = cmv[s] * 6.0f;     // cm / (1.0/6)
  const float gl = gleak[s];
  const float gv = gl * vleak[s];
  const float dbase = cmt + gl + 1e-8f;

  // ---- register-resident main tables: this quarter's 8 j-quads ----
  float4 ta[8], tb[8], tw[8];
  {
    const float4* Ab = A4 + (qt * 8) * Ssz + s;
    const float4* Bb = B4 + (qt * 8) * Ssz + s;
    const float4* Wb = W4 + (qt * 8) * Ssz + s;
    #pragma unroll
    for (int q = 0; q < 8; ++q) {
      ta[q] = Ab[q * Ssz];
      tb[q] = Bb[q * Ssz];
      tw[q] = Wb[q * Ssz];
    }
  }
  __syncthreads();

  #pragma unroll 1
  for (int cb = 0; cb < BT; cb += R) {
    // ---- sensory partials over this quarter's i-range (4 quads) ----
    float sn[R] = {0.f, 0.f, 0.f, 0.f}, sd[R] = {0.f, 0.f, 0.f, 0.f};
    #pragma unroll
    for (int q = 0; q < 4; ++q) {
      int iq = qt * 4 + q;
      float4 a4 = A4s[iq * Ssz + s];
      float4 b4 = B4s[iq * Ssz + s];
      float4 w4 = W4s[iq * Ssz + s];
      float4 xq[R];
      #pragma unroll
      for (int r = 0; r < R; ++r) xq[r] = *(const float4*)&xsh[cb + r][iq * 4];
      #pragma unroll
      for (int jj = 0; jj < 4; ++jj) {
        float av = (&a4.x)[jj], bv = (&b4.x)[jj], wv = (&w4.x)[jj];
        #pragma unroll
        for (int r = 0; r < R; ++r) {
          float arg = fmaf(av, (&xq[r].x)[jj], bv);
          float u = __builtin_amdgcn_exp2f(arg);
          float sig = __builtin_amdgcn_rcpf(1.0f + u);
          sn[r] = fmaf(wv, sig, sn[r]);
          sd[r] = fmaf(fabsf(wv), sig, sd[r]);
        }
      }
    }

    // ---- 6 ODE unfolds over this chunk's R rows ----
    #pragma unroll 1
    for (int it = 0; it < 6; ++it) {
      float num[R], den[R];
      #pragma unroll
      for (int r = 0; r < R; ++r) { num[r] = sn[r]; den[r] = sd[r]; }

      #pragma unroll
      for (int q8 = 0; q8 < 8; ++q8) {
        float4 vc[R];
        #pragma unroll
        for (int r = 0; r < R; ++r) vc[r] = *(const float4*)&vsh[cb + r][qt * 32 + q8 * 4];
        #pragma unroll
        for (int jj = 0; jj < 4; ++jj) {
          float av = (&ta[q8].x)[jj], bv = (&tb[q8].x)[jj], wv = (&tw[q8].x)[jj];
          #pragma unroll
          for (int r = 0; r < R; ++r) {
            float arg = fmaf(av, (&vc[r].x)[jj], bv);
            float u = __builtin_amdgcn_exp2f(arg);
            float sig = __builtin_amdgcn_rcpf(1.0f + u);
            num[r] = fmaf(wv, sig, num[r]);
            den[r] = fmaf(fabsf(wv), sig, den[r]);
          }
        }
      }

      #pragma unroll
      for (int r = 0; r < R; ++r) { redn[qt][r][s] = num[r]; redd[qt][r][s] = den[r]; }
      __syncthreads();                 // B1: redn visible; all vsh reads done
      // quarter qt finalizes row cb+qt (only this thread touches vsh[cb+qt][s])
      float fn = redn[0][qt][s] + redn[1][qt][s] + redn[2][qt][s] + redn[3][qt][s];
      float fd = redd[0][qt][s] + redd[1][qt][s] + redd[2][qt][s] + redd[3][qt][s];
      float vo = vsh[cb + qt][s];
      float nn = fmaf(cmt, vo, gv) + fn;
      float dd = dbase + fd;
      vsh[cb + qt][s] = nn * __builtin_amdgcn_rcpf(dd);
      __syncthreads();                 // B2: vsh writes visible; redn free for next unfold
    }
  }

  // ---- outputs: [B*32] motor affine, then [B*128] v_pre ----
  for (int k = t; k < BT * Ssz; k += NT) {
    int r = k >> 7, ss = k & 127;
    out[Bsz * MOTOR + (b0 + r) * Ssz + ss] = vsh[r][ss];
  }
  for (int k = t; k < BT * MOTOR; k += NT) {
    int r = k >> 5, m = k & 31;
    out[(b0 + r) * MOTOR + m] = fmaf(vsh[r][m], ow[m], ob[m]);
  }
}

extern "C" void kernel_launch(void* const* d_in, const int* in_sizes, int n_in,
                              void* d_out, int out_size, void* d_ws, size_t ws_size,
                              hipStream_t stream) {
  const float* inputs = (const float*)d_in[0];
  const float* states = (const float*)d_in[1];
  const float* gleak  = (const float*)d_in[2];
  const float* vleak  = (const float*)d_in[3];
  const float* cmv    = (const float*)d_in[4];
  const float* w      = (const float*)d_in[5];
  const float* sigma  = (const float*)d_in[6];
  const float* mu     = (const float*)d_in[7];
  const float* erev   = (const float*)d_in[8];
  const float* sw     = (const float*)d_in[9];
  const float* ssig   = (const float*)d_in[10];
  const float* smu    = (const float*)d_in[11];
  const float* serev  = (const float*)d_in[12];
  const float* smask  = (const float*)d_in[13];
  const float* ssmask = (const float*)d_in[14];
  const float* iw     = (const float*)d_in[15];
  const float* ib     = (const float*)d_in[16];
  const float* ow     = (const float*)d_in[17];
  const float* ob     = (const float*)d_in[18];

  char* ws = (char*)d_ws;
  float4* A4  = (float4*)(ws);                   // 32*128*16 = 65536
  float4* B4  = (float4*)(ws + 65536);           // 65536
  float4* W4  = (float4*)(ws + 131072);          // 65536
  float4* A4s = (float4*)(ws + 196608);          // 16*128*16 = 32768
  float4* B4s = (float4*)(ws + 229376);          // 32768
  float4* W4s = (float4*)(ws + 262144);          // 32768  (total 294912 B)
  float* out = (float*)d_out;

  constexpr int prep_items = (Ssz / 4) * Ssz + (Isz / 4) * Ssz;   // 6144
  ltc_prep<<<(prep_items + 255) / 256, 256, 0, stream>>>(
      w, sigma, mu, erev, smask, sw, ssig, smu, serev, ssmask, A4, B4, W4, A4s, B4s, W4s);
  ltc_main<<<Bsz / BT, NT, 0, stream>>>(
      inputs, states, gleak, vleak, cmv, iw, ib, ow, ob, A4, B4, W4, A4s, B4s, W4s, out);
}